// Round 7
// baseline (100.609 us; speedup 1.0000x reference)
//
#include <hip/hip_runtime.h>
#include <math.h>

// LearnableLPDistance: A,B [1,8,512,64] f32, p_raw [1] f32.
// p = softplus(p_raw)+1e-10; Lp-normalize rows; out[h,n,m] = 1 - 0.5*Lp(An[n]-Bn[m]).
//
// Single-gather |d|^p: one 768-entry log-indexed table (12 octaves e=[116,128) x 64
// mantissa bins, geometric-midpoint^p values), replicated 16x (dword addr idx*16+rep).
// Per term: sub + ubfe + add + clamp(med3) + lshl_add + ds_read_b32 + fmac
// (~6 VALU + 1 LDS vs R6's ~16.5 VALU + 2 LDS). Row norms use exact trans (0.4% of work).

#define EPSF 1e-10f
#define NROW 512
#define DDIM 64
#define TSTRIDE 66      // tile row stride in dwords
#define TB 32           // 32x32 output tile
#define TBL_N 768       // 12 octaves x 64 mantissa bins
#define TBL_REP 16
#define TBL_BIAS 7424   // 116*64: ubfe value of the first covered bin

__device__ __forceinline__ float hw_log2(float x){ return __builtin_amdgcn_logf(x); }
__device__ __forceinline__ float hw_exp2(float x){ return __builtin_amdgcn_exp2f(x); }
__device__ __forceinline__ float powp(float x, float p){ return hw_exp2(p*hw_log2(x)); }
__device__ __forceinline__ float softplusf(float x){ return fmaxf(x,0.f)+log1pf(expf(-fabsf(x))); }

// d^p via one replicated-table gather. Bits 17..30 of f32 = (exp<<6)|top6mant —
// sign excluded by the 14-bit field. idx clamped to [0,767] (med3).
#define TBL_POW(x_) ({                                                    \
    const int t__ = (int)((__float_as_uint(x_) >> 17) & 16383u) - TBL_BIAS; \
    const int i__ = t__ < 0 ? 0 : (t__ > (TBL_N-1) ? (TBL_N-1) : t__);    \
    tb[i__ << 4]; })

__global__ __launch_bounds__(256) void lp_fused_kernel(const float* __restrict__ A,
                                                       const float* __restrict__ B,
                                                       const float* __restrict__ p_raw,
                                                       float* __restrict__ out){
    __shared__ float s_T[TBL_N * TBL_REP];  // 48 KB, entry idx replica r at idx*16+r
    __shared__ float Ts[64 * TSTRIDE];      // 16.5 KB, rows 0..31 = A-tile, 32..63 = B-tile

    const float p     = softplusf(p_raw[0]) + EPSF;
    const float inv_p = 1.0f / p;
    const int tid = threadIdx.x;
    const float* tb = s_T + (tid & (TBL_REP - 1));  // this lane's replica base

    // Build table: 3 unique entries/thread, then 16 replica writes each
    // (replica slot rotated by tid so each wave-write spreads across banks).
    #pragma unroll
    for (int it = 0; it < 3; ++it) {
        const int k = it * 256 + tid;            // 0..767
        const int e = 116 + (k >> 6);
        const int m = k & 63;
        const float xm = __uint_as_float((unsigned)e << 23) * (1.0f + ((float)m + 0.5f) * 0.015625f);
        const float v  = powp(xm, p);
        #pragma unroll
        for (int r = 0; r < TBL_REP; ++r)
            s_T[(k << 4) + ((r + tid) & (TBL_REP - 1))] = v;
    }

    // Stage raw 32-row A and B tiles (coalesced float4).
    const int h  = blockIdx.z;
    const int n0 = blockIdx.y * TB;
    const int m0 = blockIdx.x * TB;
    const float* Ah = A + ((size_t)h * NROW + n0) * DDIM;
    const float* Bh = B + ((size_t)h * NROW + m0) * DDIM;
    #pragma unroll
    for (int k = 0; k < 4; ++k) {
        const int qq  = k * 256 + tid;
        const int row = qq >> 4;   // 0..63
        const int d4  = qq & 15;   // 0..15
        const float* src = (row < 32) ? (Ah + (size_t)row * DDIM + d4 * 4)
                                      : (Bh + (size_t)(row - 32) * DDIM + d4 * 4);
        *reinterpret_cast<float4*>(&Ts[row * TSTRIDE + d4 * 4]) = *reinterpret_cast<const float4*>(src);
    }
    __syncthreads();

    // In-place Lp row normalization, EXACT trans math (raw |x| can exceed table range).
    {
        const int r = tid >> 2;    // 0..63
        float* rowp = &Ts[r * TSTRIDE + (tid & 3) * 16];
        float s = 0.f;
        #pragma unroll
        for (int i = 0; i < 4; ++i) {
            const float4 v = *reinterpret_cast<const float4*>(rowp + i * 4);
            s += powp(fabsf(v.x), p); s += powp(fabsf(v.y), p);
            s += powp(fabsf(v.z), p); s += powp(fabsf(v.w), p);
        }
        s += __shfl_xor(s, 1, 64);
        s += __shfl_xor(s, 2, 64);
        const float inv = 1.0f / (powp(s, inv_p) + EPSF);
        #pragma unroll
        for (int i = 0; i < 4; ++i) {
            float4 v = *reinterpret_cast<float4*>(rowp + i * 4);
            v.x *= inv; v.y *= inv; v.z *= inv; v.w *= inv;
            *reinterpret_cast<float4*>(rowp + i * 4) = v;
        }
    }
    __syncthreads();

    // 2x2 register micro-tile per thread, strided (tn, tn+16) x (tm, tm+16).
    const int tn = tid >> 4;   // 0..15
    const int tm = tid & 15;   // 0..15
    float acc00 = 0.f, acc01 = 0.f, acc10 = 0.f, acc11 = 0.f;

    #pragma unroll
    for (int d = 0; d < DDIM; d += 4) {
        const float4 a0 = *reinterpret_cast<const float4*>(&Ts[ tn       * TSTRIDE + d]);
        const float4 a1 = *reinterpret_cast<const float4*>(&Ts[(tn + 16) * TSTRIDE + d]);
        const float4 b0 = *reinterpret_cast<const float4*>(&Ts[(32 + tm) * TSTRIDE + d]);
        const float4 b1 = *reinterpret_cast<const float4*>(&Ts[(48 + tm) * TSTRIDE + d]);
        acc00 += TBL_POW(a0.x - b0.x); acc00 += TBL_POW(a0.y - b0.y);
        acc00 += TBL_POW(a0.z - b0.z); acc00 += TBL_POW(a0.w - b0.w);
        acc01 += TBL_POW(a0.x - b1.x); acc01 += TBL_POW(a0.y - b1.y);
        acc01 += TBL_POW(a0.z - b1.z); acc01 += TBL_POW(a0.w - b1.w);
        acc10 += TBL_POW(a1.x - b0.x); acc10 += TBL_POW(a1.y - b0.y);
        acc10 += TBL_POW(a1.z - b0.z); acc10 += TBL_POW(a1.w - b0.w);
        acc11 += TBL_POW(a1.x - b1.x); acc11 += TBL_POW(a1.y - b1.y);
        acc11 += TBL_POW(a1.z - b1.z); acc11 += TBL_POW(a1.w - b1.w);
    }

    float* outh = out + (size_t)h * NROW * NROW;
    const int nlo = n0 + tn, nhi = n0 + tn + 16;
    const int mlo = m0 + tm, mhi = m0 + tm + 16;
    outh[(size_t)nlo * NROW + mlo] = 1.0f - 0.5f * powp(acc00, inv_p);
    outh[(size_t)nlo * NROW + mhi] = 1.0f - 0.5f * powp(acc01, inv_p);
    outh[(size_t)nhi * NROW + mlo] = 1.0f - 0.5f * powp(acc10, inv_p);
    outh[(size_t)nhi * NROW + mhi] = 1.0f - 0.5f * powp(acc11, inv_p);
}

extern "C" void kernel_launch(void* const* d_in, const int* in_sizes, int n_in,
                              void* d_out, int out_size, void* d_ws, size_t ws_size,
                              hipStream_t stream) {
    const float* A     = (const float*)d_in[0];
    const float* B     = (const float*)d_in[1];
    const float* p_raw = (const float*)d_in[2];
    float* out = (float*)d_out;

    lp_fused_kernel<<<dim3(16, 16, 8), dim3(256), 0, stream>>>(A, B, p_raw, out);
}

// Round 12
// 87.776 us; speedup vs baseline: 1.1462x; 1.1462x over previous
//
#include <hip/hip_runtime.h>
#include <math.h>

// LearnableLPDistance: A,B [1,8,512,64] f32, p_raw [1] f32.
// p = softplus(p_raw)+1e-10; Lp-normalize rows; out[h,n,m] = 1 - 0.5*Lp(An[n]-Bn[m]).
//
// Two-pipe hybrid: per float4 of dims, x/z -> single-gather LDS table (|d|^p,
// 11 octaves x 32 mantissa bins, 16-rep), y/w -> hw exp2/log2 (trans pipe).
// LDS pipe load halved vs R6 (1 gather/2 terms + halved tile reads via 64x64
// tile + 4x4 micro-tile); trans pipe (idle in R5-R7) takes the other half.

#define EPSF 1e-10f
#define NROW 512
#define DDIM 64
#define TSTRIDE 68       // tile row stride in dwords
#define TB 64            // 64x64 output tile
#define TBL_N 352        // 11 octaves (e=117..127) x 32 mantissa bins
#define TBL_REP 16
#define TBL_BIAS 3744    // 117*32

__device__ __forceinline__ float hw_log2(float x){ return __builtin_amdgcn_logf(x); }
__device__ __forceinline__ float hw_exp2(float x){ return __builtin_amdgcn_exp2f(x); }
__device__ __forceinline__ float powp(float x, float p){ return hw_exp2(p*hw_log2(x)); }
__device__ __forceinline__ float softplusf(float x){ return fmaxf(x,0.f)+log1pf(expf(-fabsf(x))); }

// |d|^p via one gather: bits[30:18] = exp<<5 | top-5 mantissa (sign excluded).
// Clamp to [0, TBL_N-1]; dword addr = idx*16 + (tid&15).
#define TPOW(x_) ({                                                        \
    int t__ = (int)((__float_as_uint(x_) >> 18) & 8191u) - TBL_BIAS;       \
    t__ = t__ < 0 ? 0 : (t__ > (TBL_N-1) ? (TBL_N-1) : t__);               \
    tb[t__ << 4]; })

// 4-dim contribution for one (a,b) pair: x,z table / y,w trans.
#define TERM4(acc_, av_, bv_)                                              \
    acc_ += TPOW((av_).x - (bv_).x);                                       \
    acc_ += powp(fabsf((av_).y - (bv_).y), p);                             \
    acc_ += TPOW((av_).z - (bv_).z);                                       \
    acc_ += powp(fabsf((av_).w - (bv_).w), p);

__global__ __launch_bounds__(256, 3) void lp_fused_kernel(const float* __restrict__ A,
                                                          const float* __restrict__ B,
                                                          const float* __restrict__ p_raw,
                                                          float* __restrict__ out){
    __shared__ float s_T[TBL_N * TBL_REP];  // 22.5 KB
    __shared__ float Ts[128 * TSTRIDE];     // 34.8 KB: rows 0..63 A-tile, 64..127 B-tile

    const float p     = softplusf(p_raw[0]) + EPSF;
    const float inv_p = 1.0f / p;
    const int tid = threadIdx.x;
    const float* tb = s_T + (tid & (TBL_REP - 1));

    // Build table: <=2 entries/thread, 16 rotated replica writes each.
    #pragma unroll
    for (int it = 0; it < 2; ++it) {
        const int k = it * 256 + tid;
        if (k < TBL_N) {
            const int e = 117 + (k >> 5);
            const int m = k & 31;
            const float xm = __uint_as_float((unsigned)e << 23) * (1.0f + ((float)m + 0.5f) * 0.03125f);
            const float v  = powp(xm, p);
            #pragma unroll
            for (int r = 0; r < TBL_REP; ++r)
                s_T[(k << 4) + ((r + tid) & (TBL_REP - 1))] = v;
        }
    }

    // Stage raw 64-row A and B tiles (coalesced float4; 8 per thread).
    const int h  = blockIdx.z;
    const int n0 = blockIdx.y * TB;
    const int m0 = blockIdx.x * TB;
    const float* Ah = A + ((size_t)h * NROW + n0) * DDIM;
    const float* Bh = B + ((size_t)h * NROW + m0) * DDIM;
    #pragma unroll
    for (int k = 0; k < 8; ++k) {
        const int qq  = k * 256 + tid;
        const int row = qq >> 4;   // 0..127
        const int d4  = qq & 15;   // 0..15
        const float* src = (row < 64) ? (Ah + (size_t)row * DDIM + d4 * 4)
                                      : (Bh + (size_t)(row - 64) * DDIM + d4 * 4);
        *reinterpret_cast<float4*>(&Ts[row * TSTRIDE + d4 * 4]) = *reinterpret_cast<const float4*>(src);
    }
    __syncthreads();

    // In-place Lp row normalization, exact trans math: 2 threads/row, 32 dims each.
    {
        const int r = tid >> 1;                 // 0..127
        float* rowp = &Ts[r * TSTRIDE + (tid & 1) * 32];
        float s = 0.f;
        #pragma unroll
        for (int i = 0; i < 8; ++i) {
            const float4 v = *reinterpret_cast<const float4*>(rowp + i * 4);
            s += powp(fabsf(v.x), p); s += powp(fabsf(v.y), p);
            s += powp(fabsf(v.z), p); s += powp(fabsf(v.w), p);
        }
        s += __shfl_xor(s, 1, 64);
        const float inv = 1.0f / (powp(s, inv_p) + EPSF);
        #pragma unroll
        for (int i = 0; i < 8; ++i) {
            float4 v = *reinterpret_cast<float4*>(rowp + i * 4);
            v.x *= inv; v.y *= inv; v.z *= inv; v.w *= inv;
            *reinterpret_cast<float4*>(rowp + i * 4) = v;
        }
    }
    __syncthreads();

    // 4x4 micro-tile, strided: rows {tn+16i}, cols {tm+16j}.
    const int tn = tid >> 4;   // 0..15
    const int tm = tid & 15;   // 0..15
    float acc[4][4];
    #pragma unroll
    for (int i = 0; i < 4; ++i)
        #pragma unroll
        for (int j = 0; j < 4; ++j) acc[i][j] = 0.f;

    #pragma unroll 2
    for (int d = 0; d < DDIM; d += 4) {
        float4 a[4], b[4];
        #pragma unroll
        for (int i = 0; i < 4; ++i) {
            a[i] = *reinterpret_cast<const float4*>(&Ts[(tn + 16 * i) * TSTRIDE + d]);
            b[i] = *reinterpret_cast<const float4*>(&Ts[(64 + tm + 16 * i) * TSTRIDE + d]);
        }
        #pragma unroll
        for (int i = 0; i < 4; ++i)
            #pragma unroll
            for (int j = 0; j < 4; ++j) {
                TERM4(acc[i][j], a[i], b[j]);
            }
    }

    float* outh = out + (size_t)h * NROW * NROW;
    #pragma unroll
    for (int i = 0; i < 4; ++i) {
        const int n = n0 + tn + 16 * i;
        #pragma unroll
        for (int j = 0; j < 4; ++j) {
            const int m = m0 + tm + 16 * j;
            outh[(size_t)n * NROW + m] = 1.0f - 0.5f * powp(acc[i][j], inv_p);
        }
    }
}

extern "C" void kernel_launch(void* const* d_in, const int* in_sizes, int n_in,
                              void* d_out, int out_size, void* d_ws, size_t ws_size,
                              hipStream_t stream) {
    const float* A     = (const float*)d_in[0];
    const float* B     = (const float*)d_in[1];
    const float* p_raw = (const float*)d_in[2];
    float* out = (float*)d_out;

    lp_fused_kernel<<<dim3(8, 8, 8), dim3(256), 0, stream>>>(A, B, p_raw, out);
}